// Round 9
// baseline (189.373 us; speedup 1.0000x reference)
//
#include <hip/hip_runtime.h>
#include <hip/hip_bf16.h>
#include <stdint.h>

#define NROWS 8192
#define NDIM  512
#define MARGIN 0.3f
#define NT    2080     // 64*65/2 upper-triangular 128x128 blocks

typedef __attribute__((ext_vector_type(16))) float floatx16;
typedef __attribute__((ext_vector_type(8)))  int   intx8;

// pack 4 floats -> 4 OCP e4m3 bytes (HW cvt, RNE, saturating)
__device__ inline unsigned cvt4_fp8(float4 f) {
  int v = 0;
  v = __builtin_amdgcn_cvt_pk_fp8_f32(f.x, f.y, v, false);
  v = __builtin_amdgcn_cvt_pk_fp8_f32(f.z, f.w, v, true);
  return (unsigned)v;
}

// fp32 -> fp8 e4m3, fully coalesced: lane i reads float4 i, writes u32 i.
// Thread 0 zero-inits the fused-reduce accumulator+counter (stream-ordered
// before loss_kernel).
__global__ void convert_kernel(const float4* __restrict__ in, unsigned* __restrict__ out,
                               float* __restrict__ gacc, unsigned* __restrict__ gcnt) {
  int i = blockIdx.x * blockDim.x + threadIdx.x;
  if (i == 0) { *gacc = 0.f; *gcnt = 0u; }
  out[i] = cvt4_fp8(in[i]);
}

// R24: DIRECT-FROM-GLOBAL fragments. NO LDS, NO barriers, NO DMA.
// R0-R8 evidence: every staged variant (8/12/16/32 waves per CU, 1/2/3-stage,
// counted vmcnt, raw barriers) lands at 38-72us with MfmaUtil <=13% and no
// pipe near ceiling — the synchronized stage->barrier->consume cycle IS the
// stall (R8: 32 waves/CU resident, 72us, pure barrier convoy). X-fp8 is
// 4 MiB (< one XCD L2), so staging buys nothing: load MFMA fragments
// straight from global. A-fragment for 32x32x64 fp8: lane (g,m32) reads 32
// consecutive bytes at row*512 + kt*64 + g*32 — 2 x global_load_dwordx4;
// one wave-instruction touches 32 full 64B lines, zero waste (lanes 0-31
// cols [g*32,16), lanes 32-63 next 16B). Byte-identical to the verified
// LDS-swizzle path -> layout risk nil. Each wave = independent 8-step
// load+MFMA chain; compiler software-pipelines; TLP hides L2 latency.
// Manual depth-1 prefetch caps live frags ~48 VGPR (R4 spill lesson).
// Pipe floors: MFMA 7.4us, L1-return 6.8us, L2 266MB ~7.7us.
__launch_bounds__(512, 1)
__global__ void loss_kernel(const unsigned char* __restrict__ Xb, const int* __restrict__ tg,
                            float* __restrict__ gacc, unsigned* __restrict__ gcnt,
                            float* __restrict__ out) {
  __shared__ float red[8];

  // super-tile decode (8 diagonal supers of 36, then 28 off-diag of 64) —
  // exact R0 decode (best-run proven).
  int t = blockIdx.x;
  int bi, bj;
  if (t < 288) {
    int si = t / 36;
    int q  = t - si * 36;
    int ii = 0;
    while (q >= 8 - ii) { q -= 8 - ii; ii++; }
    bi = si * 8 + ii;
    bj = si * 8 + ii + q;
  } else {
    int q = t - 288;
    int s = q >> 6, r = q & 63;
    int si = 0;
    while (s >= 7 - si) { s -= 7 - si; si++; }
    int sj = si + 1 + s;
    bi = si * 8 + (r >> 3);
    bj = sj * 8 + (r & 7);
  }

  const int tid  = threadIdx.x;
  const int lane = tid & 63;
  const int w    = tid >> 6;             // 0..7
  const int wm   = w >> 2, wn = w & 3;   // 2x4 waves, 64x32 each
  const int g    = lane >> 5;            // MFMA k-group (0/1)
  const int m32  = lane & 31;            // MFMA row/col within 32

  const int rowBase = bi * 128;
  const int colBase = bj * 128;

  // per-lane fragment base pointers; row stride = 512 B = 32 int4.
  // k index within row: kt*64 + g*32 + [0,32) -> int4 offsets kt*4, kt*4+1.
  const int4* pA0 = (const int4*)(Xb + (size_t)(rowBase + wm * 64 + m32) * NDIM + g * 32);
  const int4* pA1 = (const int4*)(Xb + (size_t)(rowBase + wm * 64 + 32 + m32) * NDIM + g * 32);
  const int4* pB  = (const int4*)(Xb + (size_t)(colBase + wn * 32 + m32) * NDIM + g * 32);

  floatx16 acc[2];
  acc[0] = (floatx16)(0.f);
  acc[1] = (floatx16)(0.f);

  // depth-1 software pipeline: hold current frags, prefetch next kt's 6 loads
  int4 a0lo = pA0[0], a0hi = pA0[1];
  int4 a1lo = pA1[0], a1hi = pA1[1];
  int4 blo  = pB[0],  bhi  = pB[1];

#pragma unroll
  for (int kt = 0; kt < 8; kt++) {
    int4 na0lo, na0hi, na1lo, na1hi, nblo, nbhi;
    if (kt < 7) {
      na0lo = pA0[(kt + 1) * 4]; na0hi = pA0[(kt + 1) * 4 + 1];
      na1lo = pA1[(kt + 1) * 4]; na1hi = pA1[(kt + 1) * 4 + 1];
      nblo  = pB [(kt + 1) * 4]; nbhi  = pB [(kt + 1) * 4 + 1];
    }

    intx8 af0; af0[0]=a0lo.x; af0[1]=a0lo.y; af0[2]=a0lo.z; af0[3]=a0lo.w;
               af0[4]=a0hi.x; af0[5]=a0hi.y; af0[6]=a0hi.z; af0[7]=a0hi.w;
    intx8 af1; af1[0]=a1lo.x; af1[1]=a1lo.y; af1[2]=a1lo.z; af1[3]=a1lo.w;
               af1[4]=a1hi.x; af1[5]=a1hi.y; af1[6]=a1hi.z; af1[7]=a1hi.w;
    intx8 bf;  bf[0]=blo.x;  bf[1]=blo.y;  bf[2]=blo.z;  bf[3]=blo.w;
               bf[4]=bhi.x;  bf[5]=bhi.y;  bf[6]=bhi.z;  bf[7]=bhi.w;

    acc[0] = __builtin_amdgcn_mfma_scale_f32_32x32x64_f8f6f4(
        af0, bf, acc[0],
        0 /*A fmt: fp8 e4m3*/, 0 /*B fmt: fp8 e4m3*/,
        0, 127 /*scaleA = 2^0*/, 0, 127 /*scaleB = 2^0*/);
    acc[1] = __builtin_amdgcn_mfma_scale_f32_32x32x64_f8f6f4(
        af1, bf, acc[1],
        0, 0, 0, 127, 0, 127);

    if (kt < 7) {
      a0lo = na0lo; a0hi = na0hi;
      a1lo = na1lo; a1hi = na1hi;
      blo  = nblo;  bhi  = nbhi;
    }
  }

  // Epilogue (R0-verified). 32x32 C/D layout [m74/m101]: col = lane&31,
  // row = (reg&3) + 8*(reg>>2) + 4*(lane>>5), reg in [0,16).
  float lsum = 0.f;
  const bool diag = (bi == bj);
  const int  tc   = tg[colBase + wn * 32 + m32];
  if (!diag) {
#pragma unroll
    for (int mt = 0; mt < 2; mt++) {
#pragma unroll
      for (int q = 0; q < 4; q++) {
        const int4 rlv = *(const int4*)(tg + rowBase + wm * 64 + mt * 32 + 4 * g + 8 * q);
        const int rlab[4] = {rlv.x, rlv.y, rlv.z, rlv.w};
#pragma unroll
        for (int j = 0; j < 4; j++) {
          const float s = acc[mt][q * 4 + j];
          lsum += (rlab[j] == tc) ? ((s < 1.f) ? 1.f - s : 0.f)
                                  : ((s > MARGIN) ? s : 0.f);
        }
      }
    }
    lsum *= 2.f;     // pair weight hoisted
  } else {
    const int col = colBase + wn * 32 + m32;
#pragma unroll
    for (int mt = 0; mt < 2; mt++) {
#pragma unroll
      for (int q = 0; q < 4; q++) {
        const int rbase = wm * 64 + mt * 32 + 4 * g + 8 * q;
        const int4 rlv = *(const int4*)(tg + rowBase + rbase);
        const int rlab[4] = {rlv.x, rlv.y, rlv.z, rlv.w};
#pragma unroll
        for (int j = 0; j < 4; j++) {
          const float s = acc[mt][q * 4 + j];
          float c = (rlab[j] == tc) ? ((s < 1.f) ? 1.f - s : 0.f)
                                    : ((s > MARGIN) ? s : 0.f);
          const int row = rowBase + rbase + j;
          float wgt = (row < col) ? 2.f : ((row == col) ? 1.f : 0.f);
          lsum += wgt * c;
        }
      }
    }
  }

  // block reduce -> ONE atomicAdd per block + completion counter; last
  // block finalizes out (device-scope atomics, m20; fences order acc vs cnt)
#pragma unroll
  for (int off = 32; off > 0; off >>= 1) lsum += __shfl_down(lsum, off, 64);
  if (lane == 0) red[w] = lsum;
  __syncthreads();
  if (tid == 0) {
    float s = 0.f;
#pragma unroll
    for (int i = 0; i < 8; i++) s += red[i];
    atomicAdd(gacc, s);
    __threadfence();
    const unsigned old = atomicAdd(gcnt, 1u);
    if (old == NT - 1) {
      __threadfence();
      const float total = atomicAdd(gacc, 0.f);   // coherent read-back
      out[0] = total * (1.0f / NROWS);
    }
  }
}

extern "C" void kernel_launch(void* const* d_in, const int* in_sizes, int n_in,
                              void* d_out, int out_size, void* d_ws, size_t ws_size,
                              hipStream_t stream) {
  const float* x = (const float*)d_in[0];
  const int* tg  = (const int*)d_in[1];
  float* out     = (float*)d_out;
  unsigned char* xb = (unsigned char*)d_ws;                    // fp8 X, 4 MiB
  float* gacc    = (float*)((char*)d_ws + (4u << 20));
  unsigned* gcnt = (unsigned*)((char*)d_ws + (4u << 20) + 16);

  convert_kernel<<<(NROWS * NDIM / 4) / 256, 256, 0, stream>>>(
      (const float4*)x, (unsigned*)xb, gacc, gcnt);
  loss_kernel<<<NT, 512, 0, stream>>>(xb, tg, gacc, gcnt, out);
}

// Round 10
// 136.823 us; speedup vs baseline: 1.3841x; 1.3841x over previous
//
#include <hip/hip_runtime.h>
#include <hip/hip_bf16.h>
#include <stdint.h>

#define NROWS 8192
#define NDIM  512
#define MARGIN 0.3f
#define NT    2080     // 64*65/2 upper-triangular 128x128 blocks

typedef __attribute__((ext_vector_type(16))) float floatx16;
typedef __attribute__((ext_vector_type(8)))  int   intx8;

// pack 4 floats -> 4 OCP e4m3 bytes (HW cvt, RNE, saturating)
__device__ inline unsigned cvt4_fp8(float4 f) {
  int v = 0;
  v = __builtin_amdgcn_cvt_pk_fp8_f32(f.x, f.y, v, false);
  v = __builtin_amdgcn_cvt_pk_fp8_f32(f.z, f.w, v, true);
  return (unsigned)v;
}

// fp32 -> fp8 e4m3, fully coalesced: lane i reads float4 i, writes u32 i.
// Thread 0 zero-inits the fused-reduce accumulator+counter (stream-ordered
// before loss_kernel).
__global__ void convert_kernel(const float4* __restrict__ in, unsigned* __restrict__ out,
                               float* __restrict__ gacc, unsigned* __restrict__ gcnt) {
  int i = blockIdx.x * blockDim.x + threadIdx.x;
  if (i == 0) { *gacc = 0.f; *gcnt = 0u; }
  out[i] = cvt4_fp8(in[i]);
}

__device__ inline void gload_lds16(const void* g, void* l) {
  __builtin_amdgcn_global_load_lds(
      (const __attribute__((address_space(1))) unsigned int*)g,
      (__attribute__((address_space(3))) unsigned int*)l, 16, 0, 0);
}

// R25 = R7 (best: ~38us loss, 94.7 total) with HALF the barriers + fused
// reduce. R9 post-mortem: direct-global fragments fail (VGPR=36 — compiler
// sinks loads next to MFMAs, serial L2 latency; 32-line scatter per wave
// instr). R8: 16-wave barrier groups convoy. R7's residual cost = 8 barrier
// convoys/tile. Fix: 4-stage LDS (4 x 16 KB = 64 KB -> still 2 blocks/CU at
// the 128-reg cap) -> buffer reuse distance 4 -> ONE barrier covers TWO
// stage-issues. Double-step schedule per wave (2 loads/stage, R7-proven):
//   vmcnt(2)  [stage kt landed, kt+1's 2 in flight]
//   s_barrier [seals reads of kt-2, kt-1]
//   STAGE(kt+2), STAGE(kt+3)          [overwrite bufs read at kt-2, kt-1]
//   compute kt
//   vmcnt(4)  [kt+1 landed; kt+2/kt+3 in flight]  -- NO barrier
//   compute kt+1
// vmcnt never drains to 0 until the tail (kt=6: vmcnt(2) ... vmcnt(0)).
// Raw s_barrier (no lgkm drain: all ds_reads consumed by MFMAs before it).
// R14-verified swizzle; R0-verified epilogue; R8-verified fused atomic
// reduce (device-scope atomics m20) kills the reduce launch.
__launch_bounds__(512, 4)
__global__ void loss_kernel(const unsigned char* __restrict__ Xb, const int* __restrict__ tg,
                            float* __restrict__ gacc, unsigned* __restrict__ gcnt,
                            float* __restrict__ out) {
  __shared__ __align__(16) unsigned char As[4][8192];   // 128 rows x 64 B
  __shared__ __align__(16) unsigned char Bs[4][8192];
  __shared__ float red[8];

  // super-tile decode (8 diagonal supers of 36, then 28 off-diag of 64) —
  // exact R0 decode (best-run proven).
  int t = blockIdx.x;
  int bi, bj;
  if (t < 288) {
    int si = t / 36;
    int q  = t - si * 36;
    int ii = 0;
    while (q >= 8 - ii) { q -= 8 - ii; ii++; }
    bi = si * 8 + ii;
    bj = si * 8 + ii + q;
  } else {
    int q = t - 288;
    int s = q >> 6, r = q & 63;
    int si = 0;
    while (s >= 7 - si) { s -= 7 - si; si++; }
    int sj = si + 1 + s;
    bi = si * 8 + (r >> 3);
    bj = sj * 8 + (r & 7);
  }

  const int tid  = threadIdx.x;
  const int lane = tid & 63;
  const int w    = tid >> 6;             // 0..7
  const int wm   = w >> 2, wn = w & 3;   // 2x4 waves, 64x32 each
  const int g    = lane >> 5;            // MFMA k-group (0/1)
  const int m32  = lane & 31;            // MFMA row/col within 32

  const int rowBase = bi * 128;
  const int colBase = bj * 128;

  // staging: tile = 128 rows x 64 B = 8 chunks of 1 KB (16 rows each);
  // wave w stages chunk w of A and chunk w of B (2 DMA loads/wave/stage).
  // Chunk lane d: row = w*16 + (d>>2), u_phys = d&3; fetches global k-unit
  // u_log = u_phys ^ ((row>>2)&3)  (conflict-free b128 reads, R14-verified;
  // (row>>2)&3 == (srow>>2)&3 since w*16 contributes 0 mod 4).
  const int srow = lane >> 2;
  const int sup  = lane & 3;
  const int ul   = sup ^ ((srow >> 2) & 3);
  const int rloc = w * 16 + srow;
  const unsigned gA = (unsigned)((rowBase + rloc) * NDIM + ul * 16);
  const unsigned gB = (unsigned)((colBase + rloc) * NDIM + ul * 16);

#define STAGE(KT, BUF)                                                    \
  do {                                                                    \
    gload_lds16(Xb + gA + (KT) * 64, &As[BUF][w * 1024]);                 \
    gload_lds16(Xb + gB + (KT) * 64, &Bs[BUF][w * 1024]);                 \
  } while (0)

  floatx16 acc[2];
  acc[0] = (floatx16)(0.f);
  acc[1] = (floatx16)(0.f);

  // one K-step of MFMA work from buffer BUF (compile-time constant after
  // full unroll): B fragment shared across both mt.
#define COMPUTE(BUF)                                                      \
  do {                                                                    \
    intx8 bf;                                                             \
    {                                                                     \
      const int row = wn * 32 + m32;                                      \
      const int x = (row >> 2) & 3;                                       \
      int4 lo = *(const int4*)(&Bs[BUF][row * 64 + ((2 * g)     ^ x) * 16]); \
      int4 hi = *(const int4*)(&Bs[BUF][row * 64 + ((2 * g + 1) ^ x) * 16]); \
      intx8 f; f[0]=lo.x; f[1]=lo.y; f[2]=lo.z; f[3]=lo.w;                \
               f[4]=hi.x; f[5]=hi.y; f[6]=hi.z; f[7]=hi.w;                \
      bf = f;                                                             \
    }                                                                     \
    _Pragma("unroll")                                                     \
    for (int mt = 0; mt < 2; mt++) {                                      \
      const int row = wm * 64 + mt * 32 + m32;                            \
      const int x = (row >> 2) & 3;                                       \
      int4 lo = *(const int4*)(&As[BUF][row * 64 + ((2 * g)     ^ x) * 16]); \
      int4 hi = *(const int4*)(&As[BUF][row * 64 + ((2 * g + 1) ^ x) * 16]); \
      intx8 af; af[0]=lo.x; af[1]=lo.y; af[2]=lo.z; af[3]=lo.w;           \
                af[4]=hi.x; af[5]=hi.y; af[6]=hi.z; af[7]=hi.w;           \
      acc[mt] = __builtin_amdgcn_mfma_scale_f32_32x32x64_f8f6f4(          \
          af, bf, acc[mt], 0, 0, 0, 127, 0, 127);                         \
    }                                                                     \
  } while (0)

  STAGE(0, 0);
  STAGE(1, 1);

#pragma unroll
  for (int kt = 0; kt < 8; kt += 2) {
    // stage kt landed (2 oldest retired); kt+1's 2 stay in flight.
    asm volatile("s_waitcnt vmcnt(2)" ::: "memory");
    asm volatile("s_barrier" ::: "memory");        // raw: no lgkm drain
    if (kt < 6) {
      STAGE(kt + 2, (kt + 2) & 3);                 // overwrites buf read at kt-2
      STAGE(kt + 3, (kt + 3) & 3);                 // overwrites buf read at kt-1
    }
    COMPUTE(kt & 3);
    // stage kt+1 landed; kt+2/kt+3's 4 stay in flight. NO barrier needed:
    // nobody writes buf (kt+1)&3 until stage kt+5 (after the next barrier).
    if (kt < 6) asm volatile("s_waitcnt vmcnt(4)" ::: "memory");
    else        asm volatile("s_waitcnt vmcnt(0)" ::: "memory");
    COMPUTE((kt + 1) & 3);
  }

  // Epilogue (R0-verified). 32x32 C/D layout [m74/m101]: col = lane&31,
  // row = (reg&3) + 8*(reg>>2) + 4*(lane>>5), reg in [0,16).
  float lsum = 0.f;
  const bool diag = (bi == bj);
  const int  tc   = tg[colBase + wn * 32 + m32];
  if (!diag) {
#pragma unroll
    for (int mt = 0; mt < 2; mt++) {
#pragma unroll
      for (int q = 0; q < 4; q++) {
        const int4 rlv = *(const int4*)(tg + rowBase + wm * 64 + mt * 32 + 4 * g + 8 * q);
        const int rlab[4] = {rlv.x, rlv.y, rlv.z, rlv.w};
#pragma unroll
        for (int j = 0; j < 4; j++) {
          const float s = acc[mt][q * 4 + j];
          lsum += (rlab[j] == tc) ? ((s < 1.f) ? 1.f - s : 0.f)
                                  : ((s > MARGIN) ? s : 0.f);
        }
      }
    }
    lsum *= 2.f;     // pair weight hoisted
  } else {
    const int col = colBase + wn * 32 + m32;
#pragma unroll
    for (int mt = 0; mt < 2; mt++) {
#pragma unroll
      for (int q = 0; q < 4; q++) {
        const int rbase = wm * 64 + mt * 32 + 4 * g + 8 * q;
        const int4 rlv = *(const int4*)(tg + rowBase + rbase);
        const int rlab[4] = {rlv.x, rlv.y, rlv.z, rlv.w};
#pragma unroll
        for (int j = 0; j < 4; j++) {
          const float s = acc[mt][q * 4 + j];
          float c = (rlab[j] == tc) ? ((s < 1.f) ? 1.f - s : 0.f)
                                    : ((s > MARGIN) ? s : 0.f);
          const int row = rowBase + rbase + j;
          float wgt = (row < col) ? 2.f : ((row == col) ? 1.f : 0.f);
          lsum += wgt * c;
        }
      }
    }
  }

  // block reduce -> ONE atomicAdd per block + completion counter; last
  // block finalizes out (device-scope atomics, m20; fences order acc vs cnt)
#pragma unroll
  for (int off = 32; off > 0; off >>= 1) lsum += __shfl_down(lsum, off, 64);
  if (lane == 0) red[w] = lsum;
  __syncthreads();
  if (tid == 0) {
    float s = 0.f;
#pragma unroll
    for (int i = 0; i < 8; i++) s += red[i];
    atomicAdd(gacc, s);
    __threadfence();
    const unsigned old = atomicAdd(gcnt, 1u);
    if (old == NT - 1) {
      __threadfence();
      const float total = atomicAdd(gacc, 0.f);   // coherent read-back
      out[0] = total * (1.0f / NROWS);
    }
  }
#undef STAGE
#undef COMPUTE
}

extern "C" void kernel_launch(void* const* d_in, const int* in_sizes, int n_in,
                              void* d_out, int out_size, void* d_ws, size_t ws_size,
                              hipStream_t stream) {
  const float* x = (const float*)d_in[0];
  const int* tg  = (const int*)d_in[1];
  float* out     = (float*)d_out;
  unsigned char* xb = (unsigned char*)d_ws;                    // fp8 X, 4 MiB
  float* gacc    = (float*)((char*)d_ws + (4u << 20));
  unsigned* gcnt = (unsigned*)((char*)d_ws + (4u << 20) + 16);

  convert_kernel<<<(NROWS * NDIM / 4) / 256, 256, 0, stream>>>(
      (const float4*)x, (unsigned*)xb, gacc, gcnt);
  loss_kernel<<<NT, 512, 0, stream>>>(xb, tg, gacc, gcnt, out);
}

// Round 11
// 135.523 us; speedup vs baseline: 1.3973x; 1.0096x over previous
//
#include <hip/hip_runtime.h>
#include <hip/hip_bf16.h>
#include <stdint.h>

#define NROWS 8192
#define NDIM  512
#define MARGIN 0.3f
#define NT    2080     // 64*65/2 upper-triangular 128x128 blocks

typedef __attribute__((ext_vector_type(16))) float floatx16;
typedef __attribute__((ext_vector_type(8)))  int   intx8;

// pack 4 floats -> 4 OCP e4m3 bytes (HW cvt, RNE, saturating)
__device__ inline unsigned cvt4_fp8(float4 f) {
  int v = 0;
  v = __builtin_amdgcn_cvt_pk_fp8_f32(f.x, f.y, v, false);
  v = __builtin_amdgcn_cvt_pk_fp8_f32(f.z, f.w, v, true);
  return (unsigned)v;
}

// fp32 -> fp8 e4m3, fully coalesced: lane i reads float4 i, writes u32 i.
// Thread 0 zero-inits the fused-reduce accumulator+counter (stream-ordered
// before loss_kernel).
__global__ void convert_kernel(const float4* __restrict__ in, unsigned* __restrict__ out,
                               float* __restrict__ gacc, unsigned* __restrict__ gcnt) {
  int i = blockIdx.x * blockDim.x + threadIdx.x;
  if (i == 0) { *gacc = 0.f; *gcnt = 0u; }
  out[i] = cvt4_fp8(in[i]);
}

__device__ inline void gload_lds16(const void* g, void* l) {
  __builtin_amdgcn_global_load_lds(
      (const __attribute__((address_space(1))) unsigned int*)g,
      (__attribute__((address_space(3))) unsigned int*)l, 16, 0, 0);
}

// R26 = EXACT R7 loss pipeline (session best: loss ~38us, total 94.7us) +
// fused atomic reduce (verified R8-R10). R10 post-mortem: the barrier-every-
// other-step schedule was UNSOUND — vmcnt is per-wave, so COMPUTE(kt+1)
// without a barrier read chunks whose other-wave DMA wasn't certified
// landed; it also collapsed ILP (VGPR 52, 77us). R8: 16-wave barrier groups
// convoy (72us). R9: no staging = serial L2 latency (132us). Conclusion:
// R7's {128^2 tile, 8 waves x 64x32, 3-stage BK=64, 2 DMA loads/wave/stage,
// per-step vmcnt(2)->s_barrier->stage-after-barrier, 16 waves/CU} is the
// measured local optimum. This round touches NOTHING in the hot loop; only
// the final reduce is fused (removes one launch + gap).
__launch_bounds__(512, 4)
__global__ void loss_kernel(const unsigned char* __restrict__ Xb, const int* __restrict__ tg,
                            float* __restrict__ gacc, unsigned* __restrict__ gcnt,
                            float* __restrict__ out) {
  __shared__ __align__(16) unsigned char As[3][8192];   // 128 rows x 64 B
  __shared__ __align__(16) unsigned char Bs[3][8192];
  __shared__ float red[8];

  // super-tile decode (8 diagonal supers of 36, then 28 off-diag of 64) —
  // exact R0 decode.
  int t = blockIdx.x;
  int bi, bj;
  if (t < 288) {
    int si = t / 36;
    int q  = t - si * 36;
    int ii = 0;
    while (q >= 8 - ii) { q -= 8 - ii; ii++; }
    bi = si * 8 + ii;
    bj = si * 8 + ii + q;
  } else {
    int q = t - 288;
    int s = q >> 6, r = q & 63;
    int si = 0;
    while (s >= 7 - si) { s -= 7 - si; si++; }
    int sj = si + 1 + s;
    bi = si * 8 + (r >> 3);
    bj = sj * 8 + (r & 7);
  }

  const int tid  = threadIdx.x;
  const int lane = tid & 63;
  const int w    = tid >> 6;             // 0..7
  const int wm   = w >> 2, wn = w & 3;   // 2x4 waves, 64x32 each
  const int g    = lane >> 5;            // MFMA k-group (0/1)
  const int m32  = lane & 31;            // MFMA row/col within 32

  const int rowBase = bi * 128;
  const int colBase = bj * 128;

  // staging: tile = 128 rows x 64 B = 8 chunks of 1 KB (16 rows each);
  // wave w stages chunk w of A and chunk w of B (2 DMA loads/wave/stage).
  // Chunk lane d: row = w*16 + (d>>2), u_phys = d&3; fetches global k-unit
  // u_log = u_phys ^ ((row>>2)&3)  (conflict-free b128 reads, R14-verified;
  // (row>>2)&3 == (srow>>2)&3 since w*16 contributes 0 mod 4).
  const int srow = lane >> 2;
  const int sup  = lane & 3;
  const int ul   = sup ^ ((srow >> 2) & 3);
  const int rloc = w * 16 + srow;
  const unsigned gA = (unsigned)((rowBase + rloc) * NDIM + ul * 16);
  const unsigned gB = (unsigned)((colBase + rloc) * NDIM + ul * 16);

#define STAGE(KT, BUF)                                                    \
  do {                                                                    \
    gload_lds16(Xb + gA + (KT) * 64, &As[BUF][w * 1024]);                 \
    gload_lds16(Xb + gB + (KT) * 64, &Bs[BUF][w * 1024]);                 \
  } while (0)

  floatx16 acc[2];
  acc[0] = (floatx16)(0.f);
  acc[1] = (floatx16)(0.f);

  STAGE(0, 0);
  STAGE(1, 1);

#pragma unroll
  for (int kt = 0; kt < 8; kt++) {
    const int buf = kt % 3;
    // own stage kt landed (2 oldest loads retired); kt+1's 2 stay in flight.
    if (kt < 7) asm volatile("s_waitcnt vmcnt(2)" ::: "memory");
    else        asm volatile("s_waitcnt vmcnt(0)" ::: "memory");
    asm volatile("s_barrier" ::: "memory");        // raw: no lgkm drain
    if (kt < 6) STAGE(kt + 2, (kt + 2) % 3);       // distance-2 prefetch

    // B fragment first (shared across both mt), then A per mt.
    // lane holds k = g*32 + [0,32) of its row as 2 x b128 (u_log = 2g,2g+1),
    // un-swizzled via u_phys = u_log ^ ((row>>2)&3)
    intx8 bf;
    {
      const int row = wn * 32 + m32;
      const int x = (row >> 2) & 3;
      int4 lo = *(const int4*)(&Bs[buf][row * 64 + ((2 * g)     ^ x) * 16]);
      int4 hi = *(const int4*)(&Bs[buf][row * 64 + ((2 * g + 1) ^ x) * 16]);
      intx8 f; f[0]=lo.x; f[1]=lo.y; f[2]=lo.z; f[3]=lo.w;
               f[4]=hi.x; f[5]=hi.y; f[6]=hi.z; f[7]=hi.w;
      bf = f;
    }
#pragma unroll
    for (int mt = 0; mt < 2; mt++) {
      const int row = wm * 64 + mt * 32 + m32;
      const int x = (row >> 2) & 3;
      int4 lo = *(const int4*)(&As[buf][row * 64 + ((2 * g)     ^ x) * 16]);
      int4 hi = *(const int4*)(&As[buf][row * 64 + ((2 * g + 1) ^ x) * 16]);
      intx8 af; af[0]=lo.x; af[1]=lo.y; af[2]=lo.z; af[3]=lo.w;
                af[4]=hi.x; af[5]=hi.y; af[6]=hi.z; af[7]=hi.w;
      acc[mt] = __builtin_amdgcn_mfma_scale_f32_32x32x64_f8f6f4(
          af, bf, acc[mt],
          0 /*A fmt: fp8 e4m3*/, 0 /*B fmt: fp8 e4m3*/,
          0, 127 /*scaleA = 2^0*/, 0, 127 /*scaleB = 2^0*/);
    }
  }

  // Epilogue (R0-verified). 32x32 C/D layout [m74/m101]: col = lane&31,
  // row = (reg&3) + 8*(reg>>2) + 4*(lane>>5), reg in [0,16).
  float lsum = 0.f;
  const bool diag = (bi == bj);
  const int  tc   = tg[colBase + wn * 32 + m32];
  if (!diag) {
#pragma unroll
    for (int mt = 0; mt < 2; mt++) {
#pragma unroll
      for (int q = 0; q < 4; q++) {
        const int4 rlv = *(const int4*)(tg + rowBase + wm * 64 + mt * 32 + 4 * g + 8 * q);
        const int rlab[4] = {rlv.x, rlv.y, rlv.z, rlv.w};
#pragma unroll
        for (int j = 0; j < 4; j++) {
          const float s = acc[mt][q * 4 + j];
          lsum += (rlab[j] == tc) ? ((s < 1.f) ? 1.f - s : 0.f)
                                  : ((s > MARGIN) ? s : 0.f);
        }
      }
    }
    lsum *= 2.f;     // pair weight hoisted
  } else {
    const int col = colBase + wn * 32 + m32;
#pragma unroll
    for (int mt = 0; mt < 2; mt++) {
#pragma unroll
      for (int q = 0; q < 4; q++) {
        const int rbase = wm * 64 + mt * 32 + 4 * g + 8 * q;
        const int4 rlv = *(const int4*)(tg + rowBase + rbase);
        const int rlab[4] = {rlv.x, rlv.y, rlv.z, rlv.w};
#pragma unroll
        for (int j = 0; j < 4; j++) {
          const float s = acc[mt][q * 4 + j];
          float c = (rlab[j] == tc) ? ((s < 1.f) ? 1.f - s : 0.f)
                                    : ((s > MARGIN) ? s : 0.f);
          const int row = rowBase + rbase + j;
          float wgt = (row < col) ? 2.f : ((row == col) ? 1.f : 0.f);
          lsum += wgt * c;
        }
      }
    }
  }

  // block reduce -> ONE atomicAdd per block + completion counter; last
  // block finalizes out (device-scope atomics, m20; fences order acc vs cnt)
#pragma unroll
  for (int off = 32; off > 0; off >>= 1) lsum += __shfl_down(lsum, off, 64);
  if (lane == 0) red[w] = lsum;
  __syncthreads();
  if (tid == 0) {
    float s = 0.f;
#pragma unroll
    for (int i = 0; i < 8; i++) s += red[i];
    atomicAdd(gacc, s);
    __threadfence();
    const unsigned old = atomicAdd(gcnt, 1u);
    if (old == NT - 1) {
      __threadfence();
      const float total = atomicAdd(gacc, 0.f);   // coherent read-back
      out[0] = total * (1.0f / NROWS);
    }
  }
#undef STAGE
}

extern "C" void kernel_launch(void* const* d_in, const int* in_sizes, int n_in,
                              void* d_out, int out_size, void* d_ws, size_t ws_size,
                              hipStream_t stream) {
  const float* x = (const float*)d_in[0];
  const int* tg  = (const int*)d_in[1];
  float* out     = (float*)d_out;
  unsigned char* xb = (unsigned char*)d_ws;                    // fp8 X, 4 MiB
  float* gacc    = (float*)((char*)d_ws + (4u << 20));
  unsigned* gcnt = (unsigned*)((char*)d_ws + (4u << 20) + 16);

  convert_kernel<<<(NROWS * NDIM / 4) / 256, 256, 0, stream>>>(
      (const float4*)x, (unsigned*)xb, gacc, gcnt);
  loss_kernel<<<NT, 512, 0, stream>>>(xb, tg, gacc, gcnt, out);
}

// Round 12
// 95.205 us; speedup vs baseline: 1.9891x; 1.4235x over previous
//
#include <hip/hip_runtime.h>
#include <hip/hip_bf16.h>
#include <stdint.h>

#define NROWS 8192
#define NDIM  512
#define MARGIN 0.3f
#define NT    2080     // 64*65/2 upper-triangular 128x128 blocks

typedef __attribute__((ext_vector_type(16))) float floatx16;
typedef __attribute__((ext_vector_type(8)))  int   intx8;

// pack 4 floats -> 4 OCP e4m3 bytes (HW cvt, RNE, saturating)
__device__ inline unsigned cvt4_fp8(float4 f) {
  int v = 0;
  v = __builtin_amdgcn_cvt_pk_fp8_f32(f.x, f.y, v, false);
  v = __builtin_amdgcn_cvt_pk_fp8_f32(f.z, f.w, v, true);
  return (unsigned)v;
}

// fp32 -> fp8 e4m3, fully coalesced: lane i reads float4 i, writes u32 i
__global__ void convert_kernel(const float4* __restrict__ in, unsigned* __restrict__ out) {
  int i = blockIdx.x * blockDim.x + threadIdx.x;
  out[i] = cvt4_fp8(in[i]);
}

__device__ inline void gload_lds16(const void* g, void* l) {
  __builtin_amdgcn_global_load_lds(
      (const __attribute__((address_space(1))) unsigned int*)g,
      (__attribute__((address_space(3))) unsigned int*)l, 16, 0, 0);
}

// R27 = BYTE-IDENTICAL revert to the R7 artifact (session best, 94.7us).
// R8-R11 post-mortems: every deviation regressed —
//   R8  16-wave barrier groups:            loss 72us (barrier convoy)
//   R9  no staging (direct-global frags):  loss 132us (serial L2 latency)
//   R10 barrier-every-other-step:          loss 77us (unsound + ILP collapse)
//   R11 fused atomic reduce tail:          loss 74us (tail perturbed regalloc:
//        VGPR 40 -> fragments not held live -> serial lgkm waits; rule #19)
// Lesson: tail/signature edits re-roll codegen for the hot loop. This file
// is the exact R7 source: 128^2 tile, 8 waves x 64x32, 3-stage BK=64 LDS,
// 2 DMA loads/wave/stage, per-step vmcnt(2) -> raw s_barrier ->
// stage-after-barrier (distance-2), R14-verified swizzle, R0-verified
// epilogue, separate partial-store + reduce kernel.
__launch_bounds__(512, 4)
__global__ void loss_kernel(const unsigned char* __restrict__ Xb, const int* __restrict__ tg,
                            float* __restrict__ partials) {
  __shared__ __align__(16) unsigned char As[3][8192];   // 128 rows x 64 B
  __shared__ __align__(16) unsigned char Bs[3][8192];
  __shared__ float red[8];

  // super-tile decode (8 diagonal supers of 36, then 28 off-diag of 64) —
  // exact R0 decode (99.4us run).
  int t = blockIdx.x;
  int bi, bj;
  if (t < 288) {
    int si = t / 36;
    int q  = t - si * 36;
    int ii = 0;
    while (q >= 8 - ii) { q -= 8 - ii; ii++; }
    bi = si * 8 + ii;
    bj = si * 8 + ii + q;
  } else {
    int q = t - 288;
    int s = q >> 6, r = q & 63;
    int si = 0;
    while (s >= 7 - si) { s -= 7 - si; si++; }
    int sj = si + 1 + s;
    bi = si * 8 + (r >> 3);
    bj = sj * 8 + (r & 7);
  }

  const int tid  = threadIdx.x;
  const int lane = tid & 63;
  const int w    = tid >> 6;             // 0..7
  const int wm   = w >> 2, wn = w & 3;   // 2x4 waves, 64x32 each
  const int g    = lane >> 5;            // MFMA k-group (0/1)
  const int m32  = lane & 31;            // MFMA row/col within 32

  const int rowBase = bi * 128;
  const int colBase = bj * 128;

  // staging: tile = 128 rows x 64 B = 8 chunks of 1 KB (16 rows each);
  // wave w stages chunk w of A and chunk w of B (2 DMA loads/wave/stage).
  // Chunk lane d: row = w*16 + (d>>2), u_phys = d&3; fetches global k-unit
  // u_log = u_phys ^ ((row>>2)&3)  (conflict-free b128 reads, R14-verified;
  // (row>>2)&3 == (srow>>2)&3 since w*16 contributes 0 mod 4).
  const int srow = lane >> 2;
  const int sup  = lane & 3;
  const int ul   = sup ^ ((srow >> 2) & 3);
  const int rloc = w * 16 + srow;
  const unsigned gA = (unsigned)((rowBase + rloc) * NDIM + ul * 16);
  const unsigned gB = (unsigned)((colBase + rloc) * NDIM + ul * 16);

#define STAGE(KT, BUF)                                                    \
  do {                                                                    \
    gload_lds16(Xb + gA + (KT) * 64, &As[BUF][w * 1024]);                 \
    gload_lds16(Xb + gB + (KT) * 64, &Bs[BUF][w * 1024]);                 \
  } while (0)

  floatx16 acc[2];
  acc[0] = (floatx16)(0.f);
  acc[1] = (floatx16)(0.f);

  STAGE(0, 0);
  STAGE(1, 1);

#pragma unroll
  for (int kt = 0; kt < 8; kt++) {
    const int buf = kt % 3;
    // own stage kt landed (2 oldest loads retired); kt+1's 2 stay in flight.
    if (kt < 7) asm volatile("s_waitcnt vmcnt(2)" ::: "memory");
    else        asm volatile("s_waitcnt vmcnt(0)" ::: "memory");
    asm volatile("s_barrier" ::: "memory");        // raw: no lgkm drain
    if (kt < 6) STAGE(kt + 2, (kt + 2) % 3);       // distance-2 prefetch

    // B fragment first (shared across both mt), then A per mt.
    // lane holds k = g*32 + [0,32) of its row as 2 x b128 (u_log = 2g,2g+1),
    // un-swizzled via u_phys = u_log ^ ((row>>2)&3)
    intx8 bf;
    {
      const int row = wn * 32 + m32;
      const int x = (row >> 2) & 3;
      int4 lo = *(const int4*)(&Bs[buf][row * 64 + ((2 * g)     ^ x) * 16]);
      int4 hi = *(const int4*)(&Bs[buf][row * 64 + ((2 * g + 1) ^ x) * 16]);
      intx8 f; f[0]=lo.x; f[1]=lo.y; f[2]=lo.z; f[3]=lo.w;
               f[4]=hi.x; f[5]=hi.y; f[6]=hi.z; f[7]=hi.w;
      bf = f;
    }
#pragma unroll
    for (int mt = 0; mt < 2; mt++) {
      const int row = wm * 64 + mt * 32 + m32;
      const int x = (row >> 2) & 3;
      int4 lo = *(const int4*)(&As[buf][row * 64 + ((2 * g)     ^ x) * 16]);
      int4 hi = *(const int4*)(&As[buf][row * 64 + ((2 * g + 1) ^ x) * 16]);
      intx8 af; af[0]=lo.x; af[1]=lo.y; af[2]=lo.z; af[3]=lo.w;
                af[4]=hi.x; af[5]=hi.y; af[6]=hi.z; af[7]=hi.w;
      acc[mt] = __builtin_amdgcn_mfma_scale_f32_32x32x64_f8f6f4(
          af, bf, acc[mt],
          0 /*A fmt: fp8 e4m3*/, 0 /*B fmt: fp8 e4m3*/,
          0, 127 /*scaleA = 2^0*/, 0, 127 /*scaleB = 2^0*/);
    }
  }

  // Epilogue (R0-verified). 32x32 C/D layout [m74/m101]: col = lane&31,
  // row = (reg&3) + 8*(reg>>2) + 4*(lane>>5), reg in [0,16).
  float lsum = 0.f;
  const bool diag = (bi == bj);
  const int  tc   = tg[colBase + wn * 32 + m32];
  if (!diag) {
#pragma unroll
    for (int mt = 0; mt < 2; mt++) {
#pragma unroll
      for (int q = 0; q < 4; q++) {
        const int4 rlv = *(const int4*)(tg + rowBase + wm * 64 + mt * 32 + 4 * g + 8 * q);
        const int rlab[4] = {rlv.x, rlv.y, rlv.z, rlv.w};
#pragma unroll
        for (int j = 0; j < 4; j++) {
          const float s = acc[mt][q * 4 + j];
          lsum += (rlab[j] == tc) ? ((s < 1.f) ? 1.f - s : 0.f)
                                  : ((s > MARGIN) ? s : 0.f);
        }
      }
    }
    lsum *= 2.f;     // pair weight hoisted
  } else {
    const int col = colBase + wn * 32 + m32;
#pragma unroll
    for (int mt = 0; mt < 2; mt++) {
#pragma unroll
      for (int q = 0; q < 4; q++) {
        const int rbase = wm * 64 + mt * 32 + 4 * g + 8 * q;
        const int4 rlv = *(const int4*)(tg + rowBase + rbase);
        const int rlab[4] = {rlv.x, rlv.y, rlv.z, rlv.w};
#pragma unroll
        for (int j = 0; j < 4; j++) {
          const float s = acc[mt][q * 4 + j];
          float c = (rlab[j] == tc) ? ((s < 1.f) ? 1.f - s : 0.f)
                                    : ((s > MARGIN) ? s : 0.f);
          const int row = rowBase + rbase + j;
          float wgt = (row < col) ? 2.f : ((row == col) ? 1.f : 0.f);
          lsum += wgt * c;
        }
      }
    }
  }

  // block reduce, ONE non-atomic partial store per block
#pragma unroll
  for (int off = 32; off > 0; off >>= 1) lsum += __shfl_down(lsum, off, 64);
  if (lane == 0) red[w] = lsum;
  __syncthreads();
  if (tid == 0) {
    float s = 0.f;
#pragma unroll
    for (int i = 0; i < 8; i++) s += red[i];
    partials[blockIdx.x] = s;
  }
#undef STAGE
}

// NT partials -> scalar; one 256-thread block
__global__ void reduce_kernel(const float* __restrict__ partials, float* __restrict__ out) {
  __shared__ float red[4];
  float s = 0.f;
  for (int i = threadIdx.x; i < NT; i += 256) s += partials[i];
#pragma unroll
  for (int off = 32; off > 0; off >>= 1) s += __shfl_down(s, off, 64);
  if ((threadIdx.x & 63) == 0) red[threadIdx.x >> 6] = s;
  __syncthreads();
  if (threadIdx.x == 0)
    out[0] = (red[0] + red[1] + red[2] + red[3]) * (1.0f / NROWS);
}

extern "C" void kernel_launch(void* const* d_in, const int* in_sizes, int n_in,
                              void* d_out, int out_size, void* d_ws, size_t ws_size,
                              hipStream_t stream) {
  const float* x = (const float*)d_in[0];
  const int* tg  = (const int*)d_in[1];
  float* out     = (float*)d_out;
  unsigned char* xb = (unsigned char*)d_ws;                    // fp8 X, 4 MiB
  float* partials   = (float*)((char*)d_ws + (4u << 20));      // NT floats

  convert_kernel<<<(NROWS * NDIM / 4) / 256, 256, 0, stream>>>(
      (const float4*)x, (unsigned*)xb);
  loss_kernel<<<NT, 512, 0, stream>>>(xb, tg, partials);
  reduce_kernel<<<1, 256, 0, stream>>>(partials, out);
}